// Round 1
// baseline (689.274 us; speedup 1.0000x reference)
//
#include <hip/hip_runtime.h>
#include <hip/hip_fp16.h>

typedef unsigned short u16;
typedef unsigned int   u32;
typedef __attribute__((ext_vector_type(8))) _Float16 f16x8;
typedef __attribute__((ext_vector_type(4))) float    f32x4;

#define MFMA(a,b,c) __builtin_amdgcn_mfma_f32_16x16x32_f16(a,b,c,0,0,0)

__device__ __forceinline__ u16 f2h(float f) { return __half_as_ushort(__float2half(f)); }

__device__ __forceinline__ void load_lds16(const void* g, void* l) {
    __builtin_amdgcn_global_load_lds(
        (__attribute__((address_space(1))) void*)g,
        (__attribute__((address_space(3))) void*)l,
        16, 0, 0);
}

// ---------------------------------------------------------------- converts
__global__ __launch_bounds__(256) void k_conv_x(const float* __restrict__ in, u16* __restrict__ out)
{
    int i = blockIdx.x * 256 + threadIdx.x;              // n4 = 3145728 exactly
    float4 v = ((const float4*)in)[i];
    ushort4 o; o.x = f2h(v.x); o.y = f2h(v.y); o.z = f2h(v.z); o.w = f2h(v.w);
    ((ushort4*)out)[i] = o;
}

__global__ __launch_bounds__(256) void k_conv_w(const float* __restrict__ w0, const float* __restrict__ w1,
                                                const float* __restrict__ w2, u16* __restrict__ out)
{
    const float* src = (blockIdx.y == 0) ? w0 : (blockIdx.y == 1) ? w1 : w2;
    int i = blockIdx.x * 256 + threadIdx.x;              // per-matrix n4 = 147456 exactly
    float4 v = ((const float4*)src)[i];
    ushort4 o; o.x = f2h(v.x); o.y = f2h(v.y); o.z = f2h(v.z); o.w = f2h(v.w);
    ((ushort4*)(out + (size_t)blockIdx.y * 589824))[i] = o;
}

// ---------------------------------------------------------------- QKV GEMM (C[m,n] = sum_k A[m,k]*B[n,k])
// z=0: A=x(16384x768) B=Wq -> Q[s][e]; z=1: -> K[s][e]; z=2: A=Wv(768x768) B=x -> Vt[e][s] (pre-transposed V)
__global__ __launch_bounds__(256) void k_gemm(const u16* __restrict__ xb, const u16* __restrict__ Wb,
                                              u16* __restrict__ Qw, u16* __restrict__ Kw, u16* __restrict__ Vt)
{
    __shared__ u16 As[2][128*32];
    __shared__ u16 Bs[2][128*32];
    const int tid = threadIdx.x;
    const int l = tid & 63;
    const int wr = tid >> 7, wc = (tid >> 6) & 1;        // 4 waves -> 2x2 of 64x64
    const int z = blockIdx.z, bx = blockIdx.x;
    const u16 *Ap, *Bp; u16* Cp; int m0, n0; size_t ldc;
    if (z < 2) { Ap = xb; Bp = Wb + (size_t)z*589824; Cp = (z==0)?Qw:Kw; m0=(bx/6)*128; n0=(bx%6)*128; ldc=768; }
    else       { Ap = Wb + 2*589824; Bp = xb; Cp = Vt; m0=(bx%6)*128; n0=(bx/6)*128; ldc=16384; }

    f32x4 acc[4][4];
    #pragma unroll
    for (int i=0;i<4;++i)
        #pragma unroll
        for (int j=0;j<4;++j) acc[i][j] = (f32x4){0.f,0.f,0.f,0.f};

    const int srow = tid >> 2, sg = tid & 3;
    const int wb = (tid >> 6) << 10;

    #pragma unroll
    for (int i = 0; i < 2; ++i) {                        // stage kt=0
        load_lds16(Ap + (size_t)(m0 + i*64 + srow)*768 + sg*8, (char*)&As[0][0] + i*4096 + wb);
        load_lds16(Bp + (size_t)(n0 + i*64 + srow)*768 + sg*8, (char*)&Bs[0][0] + i*4096 + wb);
    }
    __syncthreads();
    int cur = 0;
    for (int kt = 0; kt < 24; ++kt) {
        if (kt + 1 < 24) {
            const int k0 = (kt+1)*32;
            #pragma unroll
            for (int i = 0; i < 2; ++i) {
                load_lds16(Ap + (size_t)(m0 + i*64 + srow)*768 + k0 + sg*8, (char*)&As[cur^1][0] + i*4096 + wb);
                load_lds16(Bp + (size_t)(n0 + i*64 + srow)*768 + k0 + sg*8, (char*)&Bs[cur^1][0] + i*4096 + wb);
            }
        }
        f16x8 a[4], b[4];
        #pragma unroll
        for (int mi = 0; mi < 4; ++mi) a[mi] = *(const f16x8*)&As[cur][(wr*64 + mi*16 + (l&15))*32 + (l>>4)*8];
        #pragma unroll
        for (int ni = 0; ni < 4; ++ni) b[ni] = *(const f16x8*)&Bs[cur][(wc*64 + ni*16 + (l&15))*32 + (l>>4)*8];
        #pragma unroll
        for (int mi = 0; mi < 4; ++mi)
            #pragma unroll
            for (int ni = 0; ni < 4; ++ni)
                acc[mi][ni] = MFMA(a[mi], b[ni], acc[mi][ni]);
        __syncthreads();
        cur ^= 1;
    }
    const int col = l & 15, rg = (l >> 4) * 4;
    #pragma unroll
    for (int mi = 0; mi < 4; ++mi)
        #pragma unroll
        for (int ni = 0; ni < 4; ++ni)
            #pragma unroll
            for (int j = 0; j < 4; ++j)
                Cp[(size_t)(m0 + wr*64 + mi*16 + rg + j) * ldc + n0 + wc*64 + ni*16 + col] = f2h(acc[mi][ni][j]);
}

// ---------------------------------------------------------------- flash attention
// QBLK=32, KVBLK=32, 8 waves. QK split-K (wave = iq,jk,kh); PV split-D (wave = qg,dg).
// 2 barriers/iter; K(t+1)/V(t) staging overlaps softmax(t); PV lags one tile.
#define SM_SCALE 0.03608439182435161f

__global__ __launch_bounds__(512) void k_flash(const u16* __restrict__ Qg, const u16* __restrict__ Kg,
                                               const u16* __restrict__ Vtg, float* __restrict__ Og)
{
    __shared__ u16 Qs[32*768];           // [32][768], granule-swizzled  (^ row&7)
    __shared__ u16 Ks[32*768];           // same
    __shared__ u16 Vs[768*32];           // [768][32] = Vt tile, granule-swizzled (^ row&3)
    __shared__ float Ss[2][32][34];      // two split-K planes
    __shared__ u16 Ps[32][40];           // P (f16), padded to 80B rows
    __shared__ float row_m[32], row_l[32], row_sc[32];

    const int tid = threadIdx.x;
    const int w = tid >> 6, l = tid & 63;
    const int qi = 127 - (int)blockIdx.x;                // reversed: long blocks first
    const int q0 = qi * 32;
    const int NT = qi + 1;                               // causal: only tiles k0 <= q0+31
    const size_t bofs = (size_t)blockIdx.y * 4096;

    const int iq = w & 1, jk = (w >> 1) & 1, kh = w >> 2;
    const int qg = w & 1, dg = w >> 1;
    const int l15 = l & 15, l4 = l >> 4;
    const float NEG_INF = -__builtin_inff();

    if (tid < 32) { row_m[tid] = NEG_INF; row_l[tid] = 0.f; }

    const int wbase = (tid >> 6) << 10;
    #pragma unroll
    for (int i = 0; i < 6; ++i) {                        // stage Q (once)
        int u = i*512 + tid;
        int row = u / 96, g = u - row*96;
        int gd = g ^ (row & 7);
        load_lds16(Qg + ((bofs + q0 + row) * 768 + gd*8), (char*)Qs + i*8192 + wbase);
    }
    #pragma unroll
    for (int i = 0; i < 6; ++i) {                        // stage K(0)
        int u = i*512 + tid;
        int row = u / 96, g = u - row*96;
        int gd = g ^ (row & 7);
        load_lds16(Kg + ((bofs + row) * 768 + gd*8), (char*)Ks + i*8192 + wbase);
    }

    f32x4 oacc[12];
    #pragma unroll
    for (int i = 0; i < 12; ++i) oacc[i] = (f32x4){0.f,0.f,0.f,0.f};

    for (int t = 0; t < NT; ++t) {
        __syncthreads();                                 // (c') K(t), V(t-1), Ps, row_sc ready
        // ---- QK(t): split-K halves, 2 accumulators for ILP
        f32x4 s0 = (f32x4){0.f,0.f,0.f,0.f}, s1 = (f32x4){0.f,0.f,0.f,0.f};
        {
            const int qrow = iq*16 + l15, krow = jk*16 + l15;
            const char* qb = (const char*)Qs + qrow*1536;
            const char* kb = (const char*)Ks + krow*1536;
            const int qx = qrow & 7, kx = krow & 7;
            #pragma unroll
            for (int s = 0; s < 12; s += 2) {
                const int g0 = kh*48 + s*4 + l4, g1 = g0 + 4;
                f16x8 a0 = *(const f16x8*)(qb + (g0 ^ qx)*16);
                f16x8 b0 = *(const f16x8*)(kb + (g0 ^ kx)*16);
                s0 = MFMA(a0, b0, s0);
                f16x8 a1 = *(const f16x8*)(qb + (g1 ^ qx)*16);
                f16x8 b1 = *(const f16x8*)(kb + (g1 ^ kx)*16);
                s1 = MFMA(a1, b1, s1);
            }
            const int scol = jk*16 + l15, srb = iq*16 + l4*4;
            #pragma unroll
            for (int j = 0; j < 4; ++j) Ss[kh][srb + j][scol] = s0[j] + s1[j];
        }
        // ---- PV(t-1), lagged
        if (t > 0) {
            const int rb = qg*16 + l4*4;
            const float fr0 = row_sc[rb], fr1 = row_sc[rb+1], fr2 = row_sc[rb+2], fr3 = row_sc[rb+3];
            f16x8 pa = *(const f16x8*)((const char*)Ps + (qg*16 + l15)*80 + l4*16);
            #pragma unroll
            for (int ni = 0; ni < 12; ++ni) {
                const int vrow = dg*192 + ni*16 + l15;
                f16x8 vb = *(const f16x8*)((const char*)Vs + vrow*64 + ((l4 ^ (vrow & 3))*16));
                f32x4 o = oacc[ni];
                o[0] *= fr0; o[1] *= fr1; o[2] *= fr2; o[3] *= fr3;
                oacc[ni] = MFMA(pa, vb, o);
            }
        }
        __syncthreads();                                 // (b) Ss done; Ks/Vs free
        #pragma unroll
        for (int i = 0; i < 6; ++i) {                    // stage V(t) (overlaps softmax)
            int u = i*512 + tid;
            int row = u >> 2, g = u & 3;
            int gd = g ^ (row & 3);
            load_lds16(Vtg + ((size_t)row*16384 + bofs + t*32 + gd*8), (char*)Vs + i*8192 + wbase);
        }
        if (t + 1 < NT) {
            const int k0r = (t+1)*32;
            #pragma unroll
            for (int i = 0; i < 6; ++i) {                // stage K(t+1) (overlaps softmax)
                int u = i*512 + tid;
                int row = u / 96, g = u - row*96;
                int gd = g ^ (row & 7);
                load_lds16(Kg + ((bofs + k0r + row) * 768 + gd*8), (char*)Ks + i*8192 + wbase);
            }
        }
        // ---- online softmax(t): 16 threads/row, 2 cols each
        {
            const int r = tid >> 4, cp = tid & 15, c0 = cp*2;
            float a0 = (Ss[0][r][c0]   + Ss[1][r][c0]  ) * SM_SCALE;
            float a1 = (Ss[0][r][c0+1] + Ss[1][r][c0+1]) * SM_SCALE;
            const int qglob = q0 + r, kglob = t*32 + c0;
            if (kglob > qglob)     a0 = NEG_INF;
            if (kglob + 1 > qglob) a1 = NEG_INF;
            float mx = fmaxf(a0, a1);
            mx = fmaxf(mx, __shfl_xor(mx, 1));
            mx = fmaxf(mx, __shfl_xor(mx, 2));
            mx = fmaxf(mx, __shfl_xor(mx, 4));
            mx = fmaxf(mx, __shfl_xor(mx, 8));
            const float m_old = row_m[r];
            const float m_new = fmaxf(m_old, mx);        // finite from t=0 (col 0 <= q always)
            const float p0 = __expf(a0 - m_new);
            const float p1 = __expf(a1 - m_new);
            float sum = p0 + p1;
            sum += __shfl_xor(sum, 1);
            sum += __shfl_xor(sum, 2);
            sum += __shfl_xor(sum, 4);
            sum += __shfl_xor(sum, 8);
            const float sc = __expf(m_old - m_new);      // 0 at t=0
            if (cp == 0) { row_m[r] = m_new; row_l[r] = row_l[r]*sc + sum; row_sc[r] = sc; }
            ushort2 pp; pp.x = f2h(p0); pp.y = f2h(p1);
            *(ushort2*)&Ps[r][c0] = pp;
        }
    }
    __syncthreads();                                     // V(NT-1), Ps, row_sc, row_l ready
    {                                                    // final PV(NT-1)
        const int rb = qg*16 + l4*4;
        const float fr0 = row_sc[rb], fr1 = row_sc[rb+1], fr2 = row_sc[rb+2], fr3 = row_sc[rb+3];
        f16x8 pa = *(const f16x8*)((const char*)Ps + (qg*16 + l15)*80 + l4*16);
        #pragma unroll
        for (int ni = 0; ni < 12; ++ni) {
            const int vrow = dg*192 + ni*16 + l15;
            f16x8 vb = *(const f16x8*)((const char*)Vs + vrow*64 + ((l4 ^ (vrow & 3))*16));
            f32x4 o = oacc[ni];
            o[0] *= fr0; o[1] *= fr1; o[2] *= fr2; o[3] *= fr3;
            oacc[ni] = MFMA(pa, vb, o);
        }
    }
    {                                                    // epilogue: O /= l, store f32
        const int rb = qg*16 + l4*4;
        const float i0 = 1.f/row_l[rb], i1 = 1.f/row_l[rb+1], i2 = 1.f/row_l[rb+2], i3 = 1.f/row_l[rb+3];
        #pragma unroll
        for (int ni = 0; ni < 12; ++ni) {
            const size_t base = (bofs + q0 + rb) * 768 + dg*192 + ni*16 + l15;
            Og[base]        = oacc[ni][0] * i0;
            Og[base + 768]  = oacc[ni][1] * i1;
            Og[base + 1536] = oacc[ni][2] * i2;
            Og[base + 2304] = oacc[ni][3] * i3;
        }
    }
}

// ---------------------------------------------------------------- launch
extern "C" void kernel_launch(void* const* d_in, const int* in_sizes, int n_in,
                              void* d_out, int out_size, void* d_ws, size_t ws_size,
                              hipStream_t stream)
{
    const float* x  = (const float*)d_in[0];
    const float* Wq = (const float*)d_in[1];
    const float* Wk = (const float*)d_in[2];
    const float* Wv = (const float*)d_in[3];
    float* out = (float*)d_out;
    char* ws = (char*)d_ws;
    // ws layout (fp16): xb 25165824B | Wb 3538944B | Q 25165824B | K 25165824B | Vt 25165824B  (~99.4 MB)
    u16* xb = (u16*)ws;
    u16* Wb = (u16*)(ws + 25165824);
    u16* Qw = (u16*)(ws + 28704768);
    u16* Kw = (u16*)(ws + 53870592);
    u16* Vt = (u16*)(ws + 79036416);

    k_conv_x<<<12288, 256, 0, stream>>>(x, xb);
    k_conv_w<<<dim3(576, 3), 256, 0, stream>>>(Wq, Wk, Wv, Wb);
    k_gemm<<<dim3(768, 1, 3), 256, 0, stream>>>(xb, Wb, Qw, Kw, Vt);
    k_flash<<<dim3(128, 4), 512, 0, stream>>>(Qw, Kw, Vt, out);
}

// Round 4
// 515.864 us; speedup vs baseline: 1.3362x; 1.3362x over previous
//
#include <hip/hip_runtime.h>
#include <hip/hip_fp16.h>

typedef unsigned short u16;
typedef unsigned int   u32;
typedef __attribute__((ext_vector_type(8))) _Float16 f16x8;
typedef __attribute__((ext_vector_type(4))) float    f32x4;

#define MFMA(a,b,c) __builtin_amdgcn_mfma_f32_16x16x32_f16(a,b,c,0,0,0)

__device__ __forceinline__ u16 f2h(float f) { return __half_as_ushort(__float2half(f)); }

__device__ __forceinline__ void load_lds16(const void* g, void* l) {
    __builtin_amdgcn_global_load_lds(
        (__attribute__((address_space(1))) void*)g,
        (__attribute__((address_space(3))) void*)l,
        16, 0, 0);
}

// ---------------------------------------------------------------- converts
__global__ __launch_bounds__(256) void k_conv_x(const float* __restrict__ in, u16* __restrict__ out)
{
    int i = blockIdx.x * 256 + threadIdx.x;              // n4 = 3145728 exactly
    float4 v = ((const float4*)in)[i];
    ushort4 o; o.x = f2h(v.x); o.y = f2h(v.y); o.z = f2h(v.z); o.w = f2h(v.w);
    ((ushort4*)out)[i] = o;
}

__global__ __launch_bounds__(256) void k_conv_w(const float* __restrict__ w0, const float* __restrict__ w1,
                                                const float* __restrict__ w2, u16* __restrict__ out)
{
    const float* src = (blockIdx.y == 0) ? w0 : (blockIdx.y == 1) ? w1 : w2;
    int i = blockIdx.x * 256 + threadIdx.x;              // per-matrix n4 = 147456 exactly
    float4 v = ((const float4*)src)[i];
    ushort4 o; o.x = f2h(v.x); o.y = f2h(v.y); o.z = f2h(v.z); o.w = f2h(v.w);
    ((ushort4*)(out + (size_t)blockIdx.y * 589824))[i] = o;
}

// ---------------------------------------------------------------- QKV GEMM (C[m,n] = sum_k A[m,k]*B[n,k])
// z=0: A=x(16384x768) B=Wq -> Q[s][e]; z=1: -> K[s][e]; z=2: A=Wv(768x768) B=x -> Vt[e][s] (pre-transposed V)
__global__ __launch_bounds__(256) void k_gemm(const u16* __restrict__ xb, const u16* __restrict__ Wb,
                                              u16* __restrict__ Qw, u16* __restrict__ Kw, u16* __restrict__ Vt)
{
    __shared__ u16 As[2][128*32];
    __shared__ u16 Bs[2][128*32];
    const int tid = threadIdx.x;
    const int l = tid & 63;
    const int wr = tid >> 7, wc = (tid >> 6) & 1;        // 4 waves -> 2x2 of 64x64
    const int z = blockIdx.z, bx = blockIdx.x;
    const u16 *Ap, *Bp; u16* Cp; int m0, n0; size_t ldc;
    if (z < 2) { Ap = xb; Bp = Wb + (size_t)z*589824; Cp = (z==0)?Qw:Kw; m0=(bx/6)*128; n0=(bx%6)*128; ldc=768; }
    else       { Ap = Wb + 2*589824; Bp = xb; Cp = Vt; m0=(bx%6)*128; n0=(bx/6)*128; ldc=16384; }

    f32x4 acc[4][4];
    #pragma unroll
    for (int i=0;i<4;++i)
        #pragma unroll
        for (int j=0;j<4;++j) acc[i][j] = (f32x4){0.f,0.f,0.f,0.f};

    const int srow = tid >> 2, sg = tid & 3;
    const int wb = (tid >> 6) << 10;

    #pragma unroll
    for (int i = 0; i < 2; ++i) {                        // stage kt=0
        load_lds16(Ap + (size_t)(m0 + i*64 + srow)*768 + sg*8, (char*)&As[0][0] + i*4096 + wb);
        load_lds16(Bp + (size_t)(n0 + i*64 + srow)*768 + sg*8, (char*)&Bs[0][0] + i*4096 + wb);
    }
    __syncthreads();
    int cur = 0;
    for (int kt = 0; kt < 24; ++kt) {
        if (kt + 1 < 24) {
            const int k0 = (kt+1)*32;
            #pragma unroll
            for (int i = 0; i < 2; ++i) {
                load_lds16(Ap + (size_t)(m0 + i*64 + srow)*768 + k0 + sg*8, (char*)&As[cur^1][0] + i*4096 + wb);
                load_lds16(Bp + (size_t)(n0 + i*64 + srow)*768 + k0 + sg*8, (char*)&Bs[cur^1][0] + i*4096 + wb);
            }
        }
        f16x8 a[4], b[4];
        #pragma unroll
        for (int mi = 0; mi < 4; ++mi) a[mi] = *(const f16x8*)&As[cur][(wr*64 + mi*16 + (l&15))*32 + (l>>4)*8];
        #pragma unroll
        for (int ni = 0; ni < 4; ++ni) b[ni] = *(const f16x8*)&Bs[cur][(wc*64 + ni*16 + (l&15))*32 + (l>>4)*8];
        #pragma unroll
        for (int mi = 0; mi < 4; ++mi)
            #pragma unroll
            for (int ni = 0; ni < 4; ++ni)
                acc[mi][ni] = MFMA(a[mi], b[ni], acc[mi][ni]);
        __syncthreads();
        cur ^= 1;
    }
    const int col = l & 15, rg = (l >> 4) * 4;
    #pragma unroll
    for (int mi = 0; mi < 4; ++mi)
        #pragma unroll
        for (int ni = 0; ni < 4; ++ni)
            #pragma unroll
            for (int j = 0; j < 4; ++j)
                Cp[(size_t)(m0 + wr*64 + mi*16 + rg + j) * ldc + n0 + wc*64 + ni*16 + col] = f2h(acc[mi][ni][j]);
}

// ---------------------------------------------------------------- flash attention v4
// 1024 threads / 16 waves, QBLK=32, KVBLK=32. Grid 256 = 4 batches x 64 pairs;
// each block does q-blocks (127-p) then (p): constant 129 tile-steps per CU.
// QK: 4 subtiles (iq,jk) x 4-way K-split (kh) -> 16 waves, each PLAIN-stores its
// f32 partial plane Sp[kh] (full overwrite/iter, no atomics: deterministic).
// Softmax sums 4 planes in f32 (round-1 numeric path). PV split dg16,
// V global->reg prefetch, K single-buffered via global_load_lds.
#define SM_SCALE 0.03608439182435161f

__global__ __launch_bounds__(1024, 4) void k_flash(const u16* __restrict__ Qg, const u16* __restrict__ Kg,
                                                   const u16* __restrict__ Vtg, float* __restrict__ Og)
{
    __shared__ u16 Qs[32*768];          // 49152 B, granule-swizzled ^(row&7)
    __shared__ u16 Ks[32*768];          // 49152 B, same
    __shared__ float Sp[4][32][34];     // 17408 B, four f32 K-partial planes
    __shared__ u16 Ps[32][40];          // 2560 B, f16 P, 80B rows (16B-aligned frags)
    __shared__ float row_m[32], row_l[32], row_sc[32];   // 384 B
    // total 118,656 B

    const int tid = threadIdx.x;
    const int w = tid >> 6, l = tid & 63;
    const int l15 = l & 15, l4 = l >> 4;
    const int iq = w & 1, jk = (w >> 1) & 1, kh = w >> 2; // QK role
    const int dg = w;                                    // PV role: 48 e-cols per wave
    const int batch = blockIdx.x & 3, p = blockIdx.x >> 2;
    const size_t bofs = (size_t)batch * 4096;
    const float NEG_INF = -__builtin_inff();
    const int wbase = w << 10;

    for (int pass = 0; pass < 2; ++pass) {
        const int qi = pass ? p : 127 - p;               // pair (127-p, p): constant total work
        const int q0 = qi * 32;
        const int NT = qi + 1;                           // 32-wide KV tiles

        if (tid < 32) { row_m[tid] = NEG_INF; row_l[tid] = 0.f; }

        #pragma unroll
        for (int i = 0; i < 3; ++i) {                    // stage Q (once per pass)
            int u = i*1024 + tid, row = u/96, g = u - row*96, gd = g ^ (row & 7);
            load_lds16(Qg + (bofs + q0 + row)*768 + gd*8, (char*)Qs + i*16384 + wbase);
        }
        #pragma unroll
        for (int i = 0; i < 3; ++i) {                    // stage K(0)
            int u = i*1024 + tid, row = u/96, g = u - row*96, gd = g ^ (row & 7);
            load_lds16(Kg + (bofs + row)*768 + gd*8, (char*)Ks + i*16384 + wbase);
        }

        f32x4 oacc[2][3];
        #pragma unroll
        for (int a = 0; a < 2; ++a)
            #pragma unroll
            for (int b = 0; b < 3; ++b) oacc[a][b] = (f32x4){0.f,0.f,0.f,0.f};
        f16x8 vfr[3];                                    // V(t) frags, consumed at t+1

        for (int t = 0; t < NT; ++t) {
            __syncthreads();                             // Ks(t), Ps(t-1), row_sc ready; Sp free
            // ---- QK(t): wave (iq,jk,kh) -> 16x16 subtile, K-slice kh*192+[0,192)
            {
                const int qrow = iq*16 + l15, krow = jk*16 + l15;
                const char* qb = (const char*)Qs + qrow*1536;
                const char* kb = (const char*)Ks + krow*1536;
                const int qx = qrow & 7, kx = krow & 7;
                f32x4 s0 = (f32x4){0.f,0.f,0.f,0.f}, s1 = (f32x4){0.f,0.f,0.f,0.f};
                #pragma unroll
                for (int s = 0; s < 6; s += 2) {
                    const int g0 = kh*24 + s*4 + l4, g1 = g0 + 4;
                    f16x8 a0 = *(const f16x8*)(qb + (g0 ^ qx)*16);
                    f16x8 b0 = *(const f16x8*)(kb + (g0 ^ kx)*16);
                    s0 = MFMA(a0, b0, s0);
                    f16x8 a1 = *(const f16x8*)(qb + (g1 ^ qx)*16);
                    f16x8 b1 = *(const f16x8*)(kb + (g1 ^ kx)*16);
                    s1 = MFMA(a1, b1, s1);
                }
                const int sr = iq*16 + l4*4, scc = jk*16 + l15;
                #pragma unroll
                for (int j = 0; j < 4; ++j)
                    Sp[kh][sr + j][scc] = s0[j] + s1[j]; // plain store: deterministic
            }
            // ---- PV(t-1), lagged (V frags already in regs)
            if (t > 0) {
                const int rb = l4*4;
                #pragma unroll
                for (int qg = 0; qg < 2; ++qg) {
                    const float fr0 = row_sc[qg*16+rb],   fr1 = row_sc[qg*16+rb+1],
                                fr2 = row_sc[qg*16+rb+2], fr3 = row_sc[qg*16+rb+3];
                    f16x8 pa = *(const f16x8*)((const char*)&Ps[0][0] + (qg*16 + l15)*80 + l4*16);
                    #pragma unroll
                    for (int ni = 0; ni < 3; ++ni) {
                        f32x4 o = oacc[qg][ni];
                        o[0]*=fr0; o[1]*=fr1; o[2]*=fr2; o[3]*=fr3;
                        oacc[qg][ni] = MFMA(pa, vfr[ni], o);
                    }
                }
            }
            __syncthreads();                             // Sp complete; Ks, Ps free
            if (t + 1 < NT) {                            // stage K(t+1) under softmax
                #pragma unroll
                for (int i = 0; i < 3; ++i) {
                    int u = i*1024 + tid, row = u/96, g = u - row*96, gd = g ^ (row & 7);
                    load_lds16(Kg + (bofs + (t+1)*32 + row)*768 + gd*8, (char*)Ks + i*16384 + wbase);
                }
            }
            // ---- V(t) frag prefetch (global->reg, consumed next iter / final)
            {
                const u16* vb = Vtg + (size_t)(dg*48 + l15)*16384 + bofs + t*32 + l4*8;
                #pragma unroll
                for (int ni = 0; ni < 3; ++ni)
                    vfr[ni] = *(const f16x8*)(vb + (size_t)ni*262144);
            }
            // ---- online softmax(t): 32 threads/row, 1 col each
            {
                const int r = tid >> 5, c = tid & 31;
                float a = (Sp[0][r][c] + Sp[1][r][c] + Sp[2][r][c] + Sp[3][r][c]) * SM_SCALE;
                const int qglob = q0 + r, kglob = t*32 + c;
                if (kglob > qglob) a = NEG_INF;
                float mx = a;
                mx = fmaxf(mx, __shfl_xor(mx, 1));
                mx = fmaxf(mx, __shfl_xor(mx, 2));
                mx = fmaxf(mx, __shfl_xor(mx, 4));
                mx = fmaxf(mx, __shfl_xor(mx, 8));
                mx = fmaxf(mx, __shfl_xor(mx, 16));
                const float m_old = row_m[r];
                const float m_new = fmaxf(m_old, mx);    // finite for every processed tile
                const float pr = __expf(a - m_new);
                float sum = pr;
                sum += __shfl_xor(sum, 1);
                sum += __shfl_xor(sum, 2);
                sum += __shfl_xor(sum, 4);
                sum += __shfl_xor(sum, 8);
                sum += __shfl_xor(sum, 16);
                const float sc = __expf(m_old - m_new);  // 0 at t=0
                if (c == 0) { row_m[r] = m_new; row_l[r] = row_l[r]*sc + sum; row_sc[r] = sc; }
                Ps[r][c] = f2h(pr);
            }
        }
        __syncthreads();                                 // Ps(NT-1), row_sc, row_l ready
        {                                                // final PV(NT-1)
            const int rb = l4*4;
            #pragma unroll
            for (int qg = 0; qg < 2; ++qg) {
                const float fr0 = row_sc[qg*16+rb],   fr1 = row_sc[qg*16+rb+1],
                            fr2 = row_sc[qg*16+rb+2], fr3 = row_sc[qg*16+rb+3];
                f16x8 pa = *(const f16x8*)((const char*)&Ps[0][0] + (qg*16 + l15)*80 + l4*16);
                #pragma unroll
                for (int ni = 0; ni < 3; ++ni) {
                    f32x4 o = oacc[qg][ni];
                    o[0]*=fr0; o[1]*=fr1; o[2]*=fr2; o[3]*=fr3;
                    oacc[qg][ni] = MFMA(pa, vfr[ni], o);
                }
            }
        }
        {                                                // epilogue: O /= l, store f32
            const int rb = l4*4;
            #pragma unroll
            for (int qg = 0; qg < 2; ++qg) {
                const float i0 = 1.f/row_l[qg*16+rb],   i1 = 1.f/row_l[qg*16+rb+1],
                            i2 = 1.f/row_l[qg*16+rb+2], i3 = 1.f/row_l[qg*16+rb+3];
                #pragma unroll
                for (int ni = 0; ni < 3; ++ni) {
                    const size_t base = (bofs + q0 + qg*16 + rb) * 768 + dg*48 + ni*16 + l15;
                    Og[base]        = oacc[qg][ni][0] * i0;
                    Og[base + 768]  = oacc[qg][ni][1] * i1;
                    Og[base + 1536] = oacc[qg][ni][2] * i2;
                    Og[base + 2304] = oacc[qg][ni][3] * i3;
                }
            }
        }
        __syncthreads();                                 // protect LDS before next pass
    }
}

// ---------------------------------------------------------------- launch
extern "C" void kernel_launch(void* const* d_in, const int* in_sizes, int n_in,
                              void* d_out, int out_size, void* d_ws, size_t ws_size,
                              hipStream_t stream)
{
    const float* x  = (const float*)d_in[0];
    const float* Wq = (const float*)d_in[1];
    const float* Wk = (const float*)d_in[2];
    const float* Wv = (const float*)d_in[3];
    float* out = (float*)d_out;
    char* ws = (char*)d_ws;
    // ws layout (fp16): xb 25165824B | Wb 3538944B | Q 25165824B | K 25165824B | Vt 25165824B  (~99.4 MB)
    u16* xb = (u16*)ws;
    u16* Wb = (u16*)(ws + 25165824);
    u16* Qw = (u16*)(ws + 28704768);
    u16* Kw = (u16*)(ws + 53870592);
    u16* Vt = (u16*)(ws + 79036416);

    k_conv_x<<<12288, 256, 0, stream>>>(x, xb);
    k_conv_w<<<dim3(576, 3), 256, 0, stream>>>(Wq, Wk, Wv, Wb);
    k_gemm<<<dim3(768, 1, 3), 256, 0, stream>>>(xb, Wb, Qw, Kw, Vt);
    k_flash<<<256, 1024, 0, stream>>>(Qw, Kw, Vt, out);
}